// Round 1
// baseline (885.330 us; speedup 1.0000x reference)
//
#include <hip/hip_runtime.h>

#define B_   32
#define C_   128
#define L_   4096
#define FL_  9
#define DIM_ 512
#define BCL  ((size_t)B_ * C_ * L_)

typedef __attribute__((ext_vector_type(8))) short short8;
typedef __attribute__((ext_vector_type(4))) float f32x4;

__device__ __forceinline__ float gelu_f(float x) {
    return 0.5f * x * (1.0f + erff(x * 0.70710678118654752440f));
}
__device__ __forceinline__ float sigm_f(float x) {
    return 1.0f / (1.0f + expf(-x));
}
__device__ __forceinline__ unsigned short bf16_rne(float x) {
    unsigned int u = __float_as_uint(x);
    u += 0x7fffu + ((u >> 16) & 1u);
    return (unsigned short)(u >> 16);
}
__device__ __forceinline__ float bf16_to_f(unsigned short h) {
    return __uint_as_float(((unsigned int)h) << 16);
}

// ---------------- one-time weight split into bf16 hi/lo, K-major ----------------
__global__ __launch_bounds__(256) void prep_weights(
    const float* __restrict__ gw, const float* __restrict__ a1w, const float* __restrict__ a2w,
    unsigned short* __restrict__ wgh, unsigned short* __restrict__ wgl,
    unsigned short* __restrict__ a1h, unsigned short* __restrict__ a1l,
    unsigned short* __restrict__ a2h, unsigned short* __restrict__ a2l) {
    int i = blockIdx.x * 256 + threadIdx.x;
    float v; unsigned short* ph; unsigned short* pl; int idx;
    if (i < 147456) {
        int lev = i / 49152, r = i % 49152;
        int co = r / 384, k = r % 384, kp = k >> 7, ci = k & 127;
        v = gw[(((size_t)lev * C_ + co) * C_ + ci) * 3 + kp];
        ph = wgh; pl = wgl; idx = i;
    } else if (i < 147456 + 8192) {
        idx = i - 147456;
        v = a1w[idx];
        ph = a1h; pl = a1l;
    } else if (i < 147456 + 16384) {
        idx = i - 147456 - 8192;
        v = a2w[idx];
        ph = a2h; pl = a2l;
    } else return;
    unsigned short h = bf16_rne(v);
    unsigned short l = bf16_rne(v - bf16_to_f(h));
    ph[idx] = h; pl[idx] = l;
}

__device__ __forceinline__ float block_sum_256(float v, float* red) {
    #pragma unroll
    for (int off = 32; off > 0; off >>= 1) v += __shfl_down(v, off);
    const int wv = threadIdx.x >> 6, ln = threadIdx.x & 63;
    if (ln == 0) red[wv] = v;
    __syncthreads();
    return red[0] + red[1] + red[2] + red[3];
}

// ---------------- mean over L (level 0 feat), float4 ----------------
__global__ __launch_bounds__(256) void mean_kernel(const float* __restrict__ in,
                                                   float* __restrict__ feat_sum) {
    __shared__ float red[4];
    const int bc = blockIdx.x, t = threadIdx.x;
    const float4* p = (const float4*)(in + (size_t)bc * L_);
    float v = 0.f;
    #pragma unroll
    for (int it = 0; it < L_ / 1024; it++) {
        float4 x = p[t + 256 * it];
        v += x.x + x.y + x.z + x.w;
    }
    float tot = block_sum_256(v, red);
    if (t == 0) feat_sum[bc] = tot;
}

// ---------------- MLP layer: grid (N/16, samples); wave = 4 outputs, K split over 64 lanes ----
template <int K, int ACT>
__global__ __launch_bounds__(256) void mlp_layer(
    const float* __restrict__ X, const float* __restrict__ W,
    const float* __restrict__ bias, float* __restrict__ Y,
    int N, float xscale) {
    constexpr int PL = K / 64;
    const int w = threadIdx.x >> 6, ln = threadIdx.x & 63;
    const int s = blockIdx.y;
    const int o0 = blockIdx.x * 16 + w * 4;
    float xv[PL];
    const float* xr = X + (size_t)s * K + ln * PL;
    if constexpr (PL == 2) {
        float2 v = *(const float2*)xr;
        xv[0] = v.x * xscale; xv[1] = v.y * xscale;
    } else {
        #pragma unroll
        for (int i = 0; i < PL / 4; i++) {
            float4 v = *(const float4*)(xr + 4 * i);
            xv[4*i] = v.x * xscale; xv[4*i+1] = v.y * xscale;
            xv[4*i+2] = v.z * xscale; xv[4*i+3] = v.w * xscale;
        }
    }
    #pragma unroll
    for (int r = 0; r < 4; r++) {
        int o = o0 + r;
        if (o < N) {
            const float* wr = W + (size_t)o * K + ln * PL;
            float acc = 0.f;
            if constexpr (PL == 2) {
                float2 v = *(const float2*)wr;
                acc = v.x * xv[0] + v.y * xv[1];
            } else {
                #pragma unroll
                for (int i = 0; i < PL / 4; i++) {
                    float4 v = *(const float4*)(wr + 4 * i);
                    acc += v.x * xv[4*i] + v.y * xv[4*i+1] + v.z * xv[4*i+2] + v.w * xv[4*i+3];
                }
            }
            #pragma unroll
            for (int off = 32; off > 0; off >>= 1) acc += __shfl_xor(acc, off);
            if (ln == 0) {
                acc += bias[o];
                Y[(size_t)s * N + o] = ACT ? gelu_f(acc) : acc;
            }
        }
    }
}

// ---------------- MLP final layer: K=1024, 18 outputs split into lo/hi ----------------
__global__ __launch_bounds__(256) void mlp_l3(
    const float* __restrict__ X, const float* __restrict__ W, const float* __restrict__ bias,
    float* __restrict__ lo_out, float* __restrict__ hi_out) {
    constexpr int K = 2 * DIM_, PL = K / 64;
    const int w = threadIdx.x >> 6, ln = threadIdx.x & 63;
    const int s = blockIdx.y;
    const int o0 = blockIdx.x * 16 + w * 4;
    float xv[PL];
    const float* xr = X + (size_t)s * K + ln * PL;
    #pragma unroll
    for (int i = 0; i < PL / 4; i++) {
        float4 v = *(const float4*)(xr + 4 * i);
        xv[4*i] = v.x; xv[4*i+1] = v.y; xv[4*i+2] = v.z; xv[4*i+3] = v.w;
    }
    #pragma unroll
    for (int r = 0; r < 4; r++) {
        int o = o0 + r;
        if (o < 2 * FL_) {
            const float* wr = W + (size_t)o * K + ln * PL;
            float acc = 0.f;
            #pragma unroll
            for (int i = 0; i < PL / 4; i++) {
                float4 v = *(const float4*)(wr + 4 * i);
                acc += v.x * xv[4*i] + v.y * xv[4*i+1] + v.z * xv[4*i+2] + v.w * xv[4*i+3];
            }
            #pragma unroll
            for (int off = 32; off > 0; off >>= 1) acc += __shfl_xor(acc, off);
            if (ln == 0) {
                acc += bias[o];
                if (o < FL_) lo_out[s * FL_ + o] = acc;
                else         hi_out[s * FL_ + (o - FL_)] = acc;
            }
        }
    }
}

// ---------------- per-sample depthwise 9-tap conv (edge pad), float4, fused feat ----------------
__global__ __launch_bounds__(256) void dwconv_kernel(
    const float* __restrict__ in, const float* __restrict__ lo_f, const float* __restrict__ hi_f,
    float* __restrict__ out_lo, float* __restrict__ out_hi, float* __restrict__ feat_next) {
    __shared__ float s[1032];
    __shared__ float red[4];
    const int t = threadIdx.x;
    const int l0 = blockIdx.x * 1024;
    const int c = blockIdx.y, b = blockIdx.z;
    const size_t base = ((size_t)b * C_ + c) * L_;
    *(float4*)&s[4 + 4 * t] = *(const float4*)&in[base + l0 + 4 * t];
    if (t < 4) {
        int gl = l0 - 4 + t;
        s[t] = in[base + max(gl, 0)];
    } else if (t < 8) {
        int i = t - 4;
        s[1028 + i] = in[base + min(l0 + 1024 + i, L_ - 1)];
    }
    float lo[FL_], hi[FL_];
    #pragma unroll
    for (int k = 0; k < FL_; k++) { lo[k] = lo_f[b * FL_ + k]; hi[k] = hi_f[b * FL_ + k]; }
    __syncthreads();
    float oL[4] = {0, 0, 0, 0}, oH[4] = {0, 0, 0, 0};
    #pragma unroll
    for (int k = 0; k < FL_; k++) {
        #pragma unroll
        for (int r = 0; r < 4; r++) {
            float v = s[4 * t + r + k];
            oL[r] += lo[k] * v; oH[r] += hi[k] * v;
        }
    }
    *(float4*)&out_lo[base + l0 + 4 * t] = *(float4*)oL;
    *(float4*)&out_hi[base + l0 + 4 * t] = *(float4*)oH;
    if (feat_next) {
        float tot = block_sum_256(oL[0] + oL[1] + oL[2] + oL[3], red);
        if (t == 0) atomicAdd(&feat_next[b * C_ + c], tot);
    }
}

// ---------------- ortho + energy scalars ----------------
__global__ void ortho_kernel(const float* __restrict__ lo2, float* __restrict__ scal) {
    const int t = threadIdx.x;
    float smooth = 0.f, sabs2 = 0.f, amp = 0.f;
    if (t < B_) {
        const float* lo = lo2 + t * FL_;
        float ss = 0.f, sa = 0.f, sm = 0.f, prev = 0.f;
        #pragma unroll
        for (int k = 0; k < FL_; k++) {
            float v = lo[k];
            sm += fabsf(v - prev); prev = v;
            ss += v * v; sa += fabsf(v);
        }
        sm += fabsf(prev);
        float den = sqrtf(ss) + 1e-8f;
        float san = sa / den;
        sabs2 = san * san;
        amp = fabsf(ss / (den * den) - 1.0f);
        smooth = sm;
    }
    #pragma unroll
    for (int off = 32; off > 0; off >>= 1) {
        smooth += __shfl_down(smooth, off);
        sabs2  += __shfl_down(sabs2, off);
        amp    += __shfl_down(amp, off);
    }
    if (t == 0) {
        float lo_smooth = smooth / (float)(B_ * 10);
        float shift = 3.0f * (sabs2 / (float)B_) / 81.0f;
        scal[0] = 0.01f * (shift + amp / (float)B_) + 0.1f * lo_smooth;
        scal[1] = 0.0f;
    }
}

// ---------------- fused reconstruction via split-bf16 MFMA ----------------
// LT=32: LDS = 2*(34*136*2) + 2*(32*40*2) = 23.6 KB -> 6 blocks/CU (24 waves)
#define LT   32
#define SX   136
#define SA   40
template <bool HAS_ATTN>
__global__ __launch_bounds__(256, 6) void recon_kernel(
    const float* __restrict__ cur_in, const float* __restrict__ det_in,
    float* __restrict__ det_out, float* __restrict__ cur_out,
    const unsigned short* __restrict__ wgh, const unsigned short* __restrict__ wgl,
    const float* __restrict__ gb,
    const unsigned short* __restrict__ a1h, const unsigned short* __restrict__ a1l,
    const float* __restrict__ b1,
    const unsigned short* __restrict__ a2h, const unsigned short* __restrict__ a2l,
    const float* __restrict__ b2) {
    __shared__ __attribute__((aligned(16))) unsigned short Xh[(LT + 2) * SX];
    __shared__ __attribute__((aligned(16))) unsigned short Xl[(LT + 2) * SX];
    __shared__ __attribute__((aligned(16))) unsigned short aTh[LT * SA];
    __shared__ __attribute__((aligned(16))) unsigned short aTl[LT * SA];

    const int t = threadIdx.x;
    const int b = blockIdx.y;
    const int l0 = blockIdx.x * LT;
    const float* curb = cur_in + (size_t)b * (C_ * L_);

    const int w = t >> 6, ln = t & 15, q = (t >> 4) & 3;

    // prefetch det tile into registers (overlaps staging + MFMA latency)
    f32x4 dpv[2][2];
    #pragma unroll
    for (int tm = 0; tm < 2; tm++)
        #pragma unroll
        for (int tn = 0; tn < 2; tn++) {
            #pragma unroll
            for (int r = 0; r < 4; r++) {
                int co = 32 * w + 16 * tm + 4 * q + r;
                dpv[tm][tn][r] = det_in[((size_t)b * C_ + co) * L_ + l0 + 16 * tn + ln];
            }
        }

    for (int u = t; u < 64 * (LT + 2); u += 256) {
        int cp = u / (LT + 2), li = u - cp * (LT + 2);
        int gl = l0 - 1 + li;
        float v0 = 0.f, v1 = 0.f;
        if (gl >= 0 && gl < L_) {
            v0 = curb[(size_t)(2 * cp) * L_ + gl];
            v1 = curb[(size_t)(2 * cp + 1) * L_ + gl];
        }
        unsigned short h0 = bf16_rne(v0), h1 = bf16_rne(v1);
        unsigned short e0 = bf16_rne(v0 - bf16_to_f(h0)), e1 = bf16_rne(v1 - bf16_to_f(h1));
        ((unsigned int*)Xh)[li * (SX / 2) + cp] = (unsigned int)h0 | ((unsigned int)h1 << 16);
        ((unsigned int*)Xl)[li * (SX / 2) + cp] = (unsigned int)e0 | ((unsigned int)e1 << 16);
    }
    __syncthreads();

    f32x4 acc[2][2];
    #pragma unroll
    for (int tm = 0; tm < 2; tm++)
        #pragma unroll
        for (int tn = 0; tn < 2; tn++) acc[tm][tn] = (f32x4){0.f, 0.f, 0.f, 0.f};

    #pragma unroll 2
    for (int kk = 0; kk < 12; kk++) {
        const int kp = kk >> 2, ci0 = (kk & 3) * 32;
        short8 ah[2], al[2];
        #pragma unroll
        for (int tm = 0; tm < 2; tm++) {
            int row = 32 * w + 16 * tm + ln;
            ah[tm] = *(const short8*)&wgh[row * 384 + kk * 32 + q * 8];
            al[tm] = *(const short8*)&wgl[row * 384 + kk * 32 + q * 8];
        }
        #pragma unroll
        for (int tn = 0; tn < 2; tn++) {
            int lrow = 16 * tn + ln + kp;
            const short8 bh = *(const short8*)&Xh[lrow * SX + ci0 + q * 8];
            const short8 bl = *(const short8*)&Xl[lrow * SX + ci0 + q * 8];
            #pragma unroll
            for (int tm = 0; tm < 2; tm++) {
                acc[tm][tn] = __builtin_amdgcn_mfma_f32_16x16x32_bf16(ah[tm], bh, acc[tm][tn], 0, 0, 0);
                acc[tm][tn] = __builtin_amdgcn_mfma_f32_16x16x32_bf16(ah[tm], bl, acc[tm][tn], 0, 0, 0);
                acc[tm][tn] = __builtin_amdgcn_mfma_f32_16x16x32_bf16(al[tm], bh, acc[tm][tn], 0, 0, 0);
            }
        }
    }

    if (HAS_ATTN) {
        // first conv (C->C/4): wave w owns position-tile (w&1), channel-tile (w>>1)
        const int pw = w & 1, cw = w >> 1;
        f32x4 acc1 = (f32x4){0.f, 0.f, 0.f, 0.f};
        #pragma unroll
        for (int kc = 0; kc < 4; kc++) {
            int ci0 = kc * 32;
            int lrow = 16 * pw + ln + 1;
            const short8 bh = *(const short8*)&Xh[lrow * SX + ci0 + q * 8];
            const short8 bl = *(const short8*)&Xl[lrow * SX + ci0 + q * 8];
            int row = 16 * cw + ln;
            short8 fh = *(const short8*)&a1h[row * 128 + ci0 + q * 8];
            short8 fl = *(const short8*)&a1l[row * 128 + ci0 + q * 8];
            acc1 = __builtin_amdgcn_mfma_f32_16x16x32_bf16(fh, bh, acc1, 0, 0, 0);
            acc1 = __builtin_amdgcn_mfma_f32_16x16x32_bf16(fh, bl, acc1, 0, 0, 0);
            acc1 = __builtin_amdgcn_mfma_f32_16x16x32_bf16(fl, bh, acc1, 0, 0, 0);
        }
        #pragma unroll
        for (int r = 0; r < 4; r++) {
            int c32 = 16 * cw + 4 * q + r;
            int lcol = 16 * pw + ln;
            float v = gelu_f(acc1[r] + b1[c32]);
            unsigned short h = bf16_rne(v);
            aTh[lcol * SA + c32] = h;
            aTl[lcol * SA + c32] = bf16_rne(v - bf16_to_f(h));
        }
        __syncthreads();
        // second conv (C/4->C)
        f32x4 acc2[2][2];
        short8 fh2[2], fl2[2];
        #pragma unroll
        for (int tm = 0; tm < 2; tm++) {
            int row = 32 * w + 16 * tm + ln;
            fh2[tm] = *(const short8*)&a2h[row * 32 + q * 8];
            fl2[tm] = *(const short8*)&a2l[row * 32 + q * 8];
            #pragma unroll
            for (int tn = 0; tn < 2; tn++) acc2[tm][tn] = (f32x4){0.f, 0.f, 0.f, 0.f};
        }
        #pragma unroll
        for (int tn = 0; tn < 2; tn++) {
            int lrow = 16 * tn + ln;
            const short8 bh = *(const short8*)&aTh[lrow * SA + q * 8];
            const short8 bl = *(const short8*)&aTl[lrow * SA + q * 8];
            #pragma unroll
            for (int tm = 0; tm < 2; tm++) {
                acc2[tm][tn] = __builtin_amdgcn_mfma_f32_16x16x32_bf16(fh2[tm], bh, acc2[tm][tn], 0, 0, 0);
                acc2[tm][tn] = __builtin_amdgcn_mfma_f32_16x16x32_bf16(fh2[tm], bl, acc2[tm][tn], 0, 0, 0);
                acc2[tm][tn] = __builtin_amdgcn_mfma_f32_16x16x32_bf16(fl2[tm], bh, acc2[tm][tn], 0, 0, 0);
            }
        }
        #pragma unroll
        for (int tm = 0; tm < 2; tm++)
            #pragma unroll
            for (int tn = 0; tn < 2; tn++) {
                #pragma unroll
                for (int r = 0; r < 4; r++) {
                    int co = 32 * w + 16 * tm + 4 * q + r;
                    float at = sigm_f(acc2[tm][tn][r] + b2[co]);
                    float d = dpv[tm][tn][r];
                    d = d * at + d;
                    dpv[tm][tn][r] = d;
                    det_out[((size_t)b * C_ + co) * L_ + l0 + 16 * tn + ln] = d;
                }
            }
    }

    #pragma unroll
    for (int tm = 0; tm < 2; tm++)
        #pragma unroll
        for (int tn = 0; tn < 2; tn++) {
            #pragma unroll
            for (int r = 0; r < 4; r++) {
                int co = 32 * w + 16 * tm + 4 * q + r;
                int lrow = 16 * tn + ln + 1;
                float cur = bf16_to_f(Xh[lrow * SX + co]) + bf16_to_f(Xl[lrow * SX + co]);
                float g = sigm_f(acc[tm][tn][r] + gb[co]);
                cur_out[((size_t)b * C_ + co) * L_ + l0 + 16 * tn + ln] = cur + g * dpv[tm][tn][r];
            }
        }
}

static inline void run_mlp(const float* feat, const float* stat_w, const float* stat_b,
                           const float* wg1_w, const float* wg1_b,
                           const float* wg2_w, const float* wg2_b,
                           float* h1_g, float* h2_g, float* lo_out, float* hi_out,
                           hipStream_t stream) {
    mlp_layer<C_, 1><<<dim3(DIM_ / 16, B_), 256, 0, stream>>>(
        feat, stat_w, stat_b, h1_g, DIM_, 1.0f / (float)L_);
    mlp_layer<DIM_, 1><<<dim3(2 * DIM_ / 16, B_), 256, 0, stream>>>(
        h1_g, wg1_w, wg1_b, h2_g, 2 * DIM_, 1.0f);
    mlp_l3<<<dim3(2, B_), 256, 0, stream>>>(h2_g, wg2_w, wg2_b, lo_out, hi_out);
}

extern "C" void kernel_launch(void* const* d_in, const int* in_sizes, int n_in,
                              void* d_out, int out_size, void* d_ws, size_t ws_size,
                              hipStream_t stream) {
    (void)in_sizes; (void)n_in; (void)out_size; (void)ws_size;
    const float* x       = (const float*)d_in[0];
    const float* stat_w  = (const float*)d_in[1];
    const float* stat_b  = (const float*)d_in[2];
    const float* wg1_w   = (const float*)d_in[3];
    const float* wg1_b   = (const float*)d_in[4];
    const float* wg2_w   = (const float*)d_in[5];
    const float* wg2_b   = (const float*)d_in[6];
    const float* gates_w = (const float*)d_in[7];
    const float* gates_b = (const float*)d_in[8];
    const float* a1w     = (const float*)d_in[9];
    const float* a1b     = (const float*)d_in[10];
    const float* a2w     = (const float*)d_in[11];
    const float* a2b     = (const float*)d_in[12];

    float* out = (float*)d_out;
    float* yl  = out;
    float* yh0 = out + BCL;
    float* yh1 = out + 2 * BCL;
    float* yh2 = out + 3 * BCL;
    float* scal = out + 4 * BCL;
    float* lo_all = scal + 2;
    float* hi_all = lo_all + 3 * B_ * FL_;

    float* wsA   = (float*)d_ws;
    float* featA = wsA + BCL;
    float* featB = featA + B_ * C_;
    float* h1_g  = featB + B_ * C_;
    float* h2_g  = h1_g + B_ * DIM_;
    unsigned short* wgh = (unsigned short*)(h2_g + B_ * 2 * DIM_);
    unsigned short* wgl = wgh + 147456;
    unsigned short* a1h = wgl + 147456;
    unsigned short* a1l = a1h + 8192;
    unsigned short* a2h = a1l + 8192;
    unsigned short* a2l = a2h + 8192;

    prep_weights<<<dim3((147456 + 16384 + 255) / 256), 256, 0, stream>>>(
        gates_w, a1w, a2w, wgh, wgl, a1h, a1l, a2h, a2l);

    const dim3 cgrid(L_ / 1024, C_, B_);
    const dim3 rgrid(L_ / LT, B_);

    // ---- analysis level 0 ----
    mean_kernel<<<dim3(B_ * C_), 256, 0, stream>>>(x, featA);
    run_mlp(featA, stat_w, stat_b, wg1_w, wg1_b, wg2_w, wg2_b, h1_g, h2_g,
            lo_all, hi_all, stream);
    hipMemsetAsync(featB, 0, B_ * C_ * sizeof(float), stream);
    dwconv_kernel<<<cgrid, 256, 0, stream>>>(x, lo_all, hi_all, wsA, yh0, featB);
    // ---- analysis level 1 ----
    run_mlp(featB, stat_w, stat_b, wg1_w, wg1_b, wg2_w, wg2_b, h1_g, h2_g,
            lo_all + B_ * FL_, hi_all + B_ * FL_, stream);
    hipMemsetAsync(featA, 0, B_ * C_ * sizeof(float), stream);
    dwconv_kernel<<<cgrid, 256, 0, stream>>>(wsA, lo_all + B_ * FL_, hi_all + B_ * FL_, yl, yh1, featA);
    // ---- analysis level 2 ----
    run_mlp(featA, stat_w, stat_b, wg1_w, wg1_b, wg2_w, wg2_b, h1_g, h2_g,
            lo_all + 2 * B_ * FL_, hi_all + 2 * B_ * FL_, stream);
    dwconv_kernel<<<cgrid, 256, 0, stream>>>(yl, lo_all + 2 * B_ * FL_, hi_all + 2 * B_ * FL_,
                                             wsA, yh2, nullptr);
    // ---- scalars ----
    ortho_kernel<<<dim3(1), 64, 0, stream>>>(lo_all + 2 * B_ * FL_, scal);
    // ---- reconstruction: i=2 (no attn), i=1, i=0 ----
    recon_kernel<false><<<rgrid, 256, 0, stream>>>(wsA, yh2, nullptr, yl,
        wgh + 2 * 49152, wgl + 2 * 49152, gates_b + 2 * C_,
        nullptr, nullptr, nullptr, nullptr, nullptr, nullptr);
    recon_kernel<true><<<rgrid, 256, 0, stream>>>(yl, yh1, yh1, wsA,
        wgh + 1 * 49152, wgl + 1 * 49152, gates_b + 1 * C_,
        a1h + 4096, a1l + 4096, a1b + 32,
        a2h + 4096, a2l + 4096, a2b + C_);
    recon_kernel<true><<<rgrid, 256, 0, stream>>>(wsA, yh0, yh0, yl,
        wgh, wgl, gates_b,
        a1h, a1l, a1b,
        a2h, a2l, a2b);
}